// Round 5
// baseline (865.459 us; speedup 1.0000x reference)
//
#include <hip/hip_runtime.h>

#define TPB 256
#define NBLK_EDGE 256          // blocks for hist/reorder; chunking must match between them
#define BIN_SHIFT 9
#define BIN_SIZE 512           // nodes per bin
#define MAXK 1024              // max bins (N=500K -> K=977)
#define ROW_BITS 19            // N=500,000 < 2^19
#define ROW_MASK ((1u << ROW_BITS) - 1)
#define CHUNK_SHIFT 13         // source chunk = row>>13 (8192 nodes = 128KB of g0)
#define NCHUNK 64              // 2^19 >> 13
#define CAP 12288              // binsort LDS staging capacity (48KB); mean bin = 8187 edges
#define UNROLL 8               // outstanding gathers per thread in scatter kernels

typedef _Float16 half8  __attribute__((ext_vector_type(8)));
typedef _Float16 half2v __attribute__((ext_vector_type(2)));

__global__ void k_zero_int(int* __restrict__ p, int n) {
    int i = blockIdx.x * blockDim.x + threadIdx.x;
    if (i < n) p[i] = 0;
}

// Per-block LDS histogram of col>>BIN_SHIFT, merged with K atomics per block.
__global__ void k_hist(const int* __restrict__ col, int E, int chunk, int K,
                       int* __restrict__ ghist) {
    __shared__ int lh[MAXK];
    for (int k = threadIdx.x; k < K; k += blockDim.x) lh[k] = 0;
    __syncthreads();
    int s = blockIdx.x * chunk, e_ = min(s + chunk, E);
    for (int e = s + threadIdx.x; e < e_; e += blockDim.x)
        atomicAdd(&lh[col[e] >> BIN_SHIFT], 1);
    __syncthreads();
    for (int k = threadIdx.x; k < K; k += blockDim.x)
        if (lh[k]) atomicAdd(&ghist[k], lh[k]);
}

// Parallel exclusive scan over K<=MAXK bins (single block of MAXK threads).
__global__ void k_scan(const int* __restrict__ ghist, int K,
                       int* __restrict__ binBase, int* __restrict__ cursor) {
    __shared__ int tmp[MAXK];
    int tid = threadIdx.x;
    int val = (tid < K) ? ghist[tid] : 0;
    tmp[tid] = val;
    __syncthreads();
    for (int off = 1; off < MAXK; off <<= 1) {
        int v = (tid >= off) ? tmp[tid - off] : 0;
        __syncthreads();
        tmp[tid] += v;
        __syncthreads();
    }
    int incl = tmp[tid];
    int excl = incl - val;
    if (tid < K) { binBase[tid] = excl; cursor[tid] = excl; }
    if (tid == K - 1) binBase[K] = incl;  // == E
}

// Counting-sort reorder: per-block LDS hist -> block-level reservation in global
// cursor -> scatter packed edges (local_col<<19 | row) into bin-contiguous storage.
__global__ void k_reorder(const int* __restrict__ row, const int* __restrict__ col,
                          int E, int chunk, int K,
                          int* __restrict__ cursor, unsigned* __restrict__ packed) {
    __shared__ int lh[MAXK];
    for (int k = threadIdx.x; k < K; k += blockDim.x) lh[k] = 0;
    __syncthreads();
    int s = blockIdx.x * chunk, e_ = min(s + chunk, E);
    for (int e = s + threadIdx.x; e < e_; e += blockDim.x)
        atomicAdd(&lh[col[e] >> BIN_SHIFT], 1);
    __syncthreads();
    for (int k = threadIdx.x; k < K; k += blockDim.x) {
        int c = lh[k];
        lh[k] = c ? atomicAdd(&cursor[k], c) : 0;  // lh becomes running write cursor
    }
    __syncthreads();
    for (int e = s + threadIdx.x; e < e_; e += blockDim.x) {
        int c = col[e];
        int b = c >> BIN_SHIFT;
        unsigned lc = (unsigned)(c & (BIN_SIZE - 1));
        int pos = atomicAdd(&lh[b], 1);            // LDS atomic, returns slot
        packed[pos] = (lc << ROW_BITS) | (unsigned)row[e];
    }
}

// Second-level sort: within each bin, order edges by source chunk (row>>CHUNK_SHIFT)
// so scatter-gathers sweep g0 in 128KB windows (per-XCD L2 resident). In-place:
// stage segment in LDS, count, scan, write back permuted. Perf-only: oversized
// bins (>CAP, ~45 sigma out) are simply left unsorted.
__global__ void __launch_bounds__(512) k_binsort(unsigned* __restrict__ packed,
                                                 const int* __restrict__ binBase) {
    __shared__ unsigned buf[CAP];           // 48 KB
    __shared__ int cnt[NCHUNK], cur[NCHUNK];
    int bin = blockIdx.x;
    int s = binBase[bin], t = binBase[bin + 1];
    int len = t - s;
    if (len <= 0 || len > CAP) return;
    for (int c = threadIdx.x; c < NCHUNK; c += blockDim.x) cnt[c] = 0;
    __syncthreads();
    for (int i = threadIdx.x; i < len; i += blockDim.x) {
        unsigned v = packed[s + i];
        buf[i] = v;
        atomicAdd(&cnt[(v & ROW_MASK) >> CHUNK_SHIFT], 1);
    }
    __syncthreads();
    if (threadIdx.x == 0) {
        int run = 0;
        for (int c = 0; c < NCHUNK; ++c) { cur[c] = run; run += cnt[c]; }
    }
    __syncthreads();
    for (int i = threadIdx.x; i < len; i += blockDim.x) {
        unsigned v = buf[i];
        int slot = atomicAdd(&cur[(v & ROW_MASK) >> CHUNK_SHIFT], 1);
        packed[s + slot] = v;
    }
}

// Fused per-bin: degree count (LDS) -> dinv = rsqrt(deg+1) -> g0 = f16(dinv*(x@W1))
__global__ void k_deg_node1(const unsigned* __restrict__ packed, const int* __restrict__ binBase,
                            const float* __restrict__ x, const float* __restrict__ W1,
                            float* __restrict__ dinv, half8* __restrict__ g0, int N) {
    __shared__ int cnt[BIN_SIZE];
    for (int i = threadIdx.x; i < BIN_SIZE; i += blockDim.x) cnt[i] = 0;
    __syncthreads();
    int bin = blockIdx.x;
    int s = binBase[bin], t = binBase[bin + 1];
    for (int e = s + (int)threadIdx.x; e < t; e += blockDim.x)
        atomicAdd(&cnt[packed[e] >> ROW_BITS], 1);
    __syncthreads();
    int base = bin << BIN_SHIFT;
    int lim = min(BIN_SIZE, N - base);
    for (int n = threadIdx.x; n < lim; n += blockDim.x) {
        int i = base + n;
        float di = rsqrtf((float)(cnt[n] + 1));  // +1 self-loop
        dinv[i] = di;
        const float4* xv = (const float4*)(x + (size_t)i * 16);
        float4 a0 = xv[0], a1 = xv[1], a2 = xv[2], a3 = xv[3];
        float xl[16] = {a0.x, a0.y, a0.z, a0.w, a1.x, a1.y, a1.z, a1.w,
                        a2.x, a2.y, a2.z, a2.w, a3.x, a3.y, a3.z, a3.w};
        float h[8];
#pragma unroll
        for (int j = 0; j < 8; ++j) h[j] = 0.0f;
#pragma unroll
        for (int k = 0; k < 16; ++k) {
            float xk = xl[k];
#pragma unroll
            for (int j = 0; j < 8; ++j) h[j] += xk * W1[k * 8 + j];
        }
        half8 g;
#pragma unroll
        for (int j = 0; j < 8; ++j) g[j] = (_Float16)(di * h[j]);
        g0[i] = g;
    }
}

// Binned LDS scatter, 8 channels, f16 gather, chunk-sorted edge order so the
// random gathers stay inside a 128KB L2-resident window per iteration phase.
__global__ void __launch_bounds__(512) k_scatter1(
        const unsigned* __restrict__ packed, const int* __restrict__ binBase,
        const half8* __restrict__ g0, float* __restrict__ acc1, int N) {
    __shared__ float tile[8 * BIN_SIZE];  // 16 KB
    for (int i = threadIdx.x; i < 8 * BIN_SIZE; i += blockDim.x) tile[i] = 0.0f;
    __syncthreads();
    int bin = blockIdx.x;
    int s = binBase[bin], t = binBase[bin + 1];
    const int stride = blockDim.x;
    int e = s + (int)threadIdx.x;
    for (; e + (UNROLL - 1) * stride < t; e += UNROLL * stride) {
        unsigned p[UNROLL];
#pragma unroll
        for (int u = 0; u < UNROLL; ++u) p[u] = packed[e + u * stride];
        half8 v[UNROLL];
#pragma unroll
        for (int u = 0; u < UNROLL; ++u) v[u] = g0[p[u] & ROW_MASK];
#pragma unroll
        for (int u = 0; u < UNROLL; ++u) {
            int lc = (int)(p[u] >> ROW_BITS);
#pragma unroll
            for (int ch = 0; ch < 8; ++ch)
                atomicAdd(&tile[ch * BIN_SIZE + lc], (float)v[u][ch]);
        }
    }
    for (; e < t; e += stride) {
        unsigned p = packed[e];
        half8 v = g0[p & ROW_MASK];
        int lc = (int)(p >> ROW_BITS);
#pragma unroll
        for (int ch = 0; ch < 8; ++ch)
            atomicAdd(&tile[ch * BIN_SIZE + lc], (float)v[ch]);
    }
    __syncthreads();
    int base = bin << BIN_SHIFT;
    int lim = min(BIN_SIZE, N - base);
    for (int n = threadIdx.x; n < lim; n += blockDim.x) {
        half8 sv = g0[base + n];
        float4* av = (float4*)(acc1 + (size_t)(base + n) * 8);
        av[0] = make_float4(tile[0 * BIN_SIZE + n] + (float)sv[0],
                            tile[1 * BIN_SIZE + n] + (float)sv[1],
                            tile[2 * BIN_SIZE + n] + (float)sv[2],
                            tile[3 * BIN_SIZE + n] + (float)sv[3]);
        av[1] = make_float4(tile[4 * BIN_SIZE + n] + (float)sv[4],
                            tile[5 * BIN_SIZE + n] + (float)sv[5],
                            tile[6 * BIN_SIZE + n] + (float)sv[6],
                            tile[7 * BIN_SIZE + n] + (float)sv[7]);
    }
}

// h = relu(dinv*acc1 + b1); g1 = f16(dinv*(h @ W2))
__global__ void k_node2(const float* __restrict__ dinv_arr, const float* __restrict__ acc1,
                        const float* __restrict__ b1, const float* __restrict__ W2,
                        half2v* __restrict__ g1, int N) {
    int i = blockIdx.x * blockDim.x + threadIdx.x;
    if (i >= N) return;
    float dinv = dinv_arr[i];
    const float4* av = (const float4*)(acc1 + (size_t)i * 8);
    float4 lo = av[0], hi = av[1];
    float h[8] = {lo.x, lo.y, lo.z, lo.w, hi.x, hi.y, hi.z, hi.w};
    float o0 = 0.0f, o1 = 0.0f;
#pragma unroll
    for (int j = 0; j < 8; ++j) {
        float hj = fmaxf(dinv * h[j] + b1[j], 0.0f);
        o0 += hj * W2[j * 2 + 0];
        o1 += hj * W2[j * 2 + 1];
    }
    half2v g;
    g.x = (_Float16)(dinv * o0);
    g.y = (_Float16)(dinv * o1);
    g1[i] = g;
}

// Binned LDS scatter (2ch, 4B f16x2 gather; g1 = 2MB, L2-resident), chunk-sorted,
// fused with log-softmax epilogue.
__global__ void __launch_bounds__(512) k_scatter2_final(
        const unsigned* __restrict__ packed, const int* __restrict__ binBase,
        const half2v* __restrict__ g1, const float* __restrict__ dinv_arr,
        const float* __restrict__ b2, float* __restrict__ out, int N) {
    __shared__ float tile[2 * BIN_SIZE];  // 4 KB
    for (int i = threadIdx.x; i < 2 * BIN_SIZE; i += blockDim.x) tile[i] = 0.0f;
    __syncthreads();
    int bin = blockIdx.x;
    int s = binBase[bin], t = binBase[bin + 1];
    const int stride = blockDim.x;
    int e = s + (int)threadIdx.x;
    for (; e + (UNROLL - 1) * stride < t; e += UNROLL * stride) {
        unsigned p[UNROLL];
#pragma unroll
        for (int u = 0; u < UNROLL; ++u) p[u] = packed[e + u * stride];
        half2v v[UNROLL];
#pragma unroll
        for (int u = 0; u < UNROLL; ++u) v[u] = g1[p[u] & ROW_MASK];
#pragma unroll
        for (int u = 0; u < UNROLL; ++u) {
            int lc = (int)(p[u] >> ROW_BITS);
            atomicAdd(&tile[lc], (float)v[u].x);
            atomicAdd(&tile[BIN_SIZE + lc], (float)v[u].y);
        }
    }
    for (; e < t; e += stride) {
        unsigned p = packed[e];
        half2v v = g1[p & ROW_MASK];
        int lc = (int)(p >> ROW_BITS);
        atomicAdd(&tile[lc], (float)v.x);
        atomicAdd(&tile[BIN_SIZE + lc], (float)v.y);
    }
    __syncthreads();
    float bb0 = b2[0], bb1 = b2[1];
    int base = bin << BIN_SHIFT;
    int lim = min(BIN_SIZE, N - base);
    for (int n = threadIdx.x; n < lim; n += blockDim.x) {
        int i = base + n;
        float di = dinv_arr[i];
        half2v sg = g1[i];
        float o0 = di * (tile[n] + (float)sg.x) + bb0;
        float o1 = di * (tile[BIN_SIZE + n] + (float)sg.y) + bb1;
        float m = fmaxf(o0, o1);
        float lse = m + logf(expf(o0 - m) + expf(o1 - m));
        ((float2*)out)[i] = make_float2(o0 - lse, o1 - lse);
    }
}

extern "C" void kernel_launch(void* const* d_in, const int* in_sizes, int n_in,
                              void* d_out, int out_size, void* d_ws, size_t ws_size,
                              hipStream_t stream) {
    const float* x  = (const float*)d_in[0];
    const float* W1 = (const float*)d_in[1];
    const float* b1 = (const float*)d_in[2];
    const float* W2 = (const float*)d_in[3];
    const float* b2 = (const float*)d_in[4];
    const int*   ei = (const int*)d_in[5];

    const int N = in_sizes[0] / 16;
    const int E = in_sizes[5] / 2;
    const int* row = ei;
    const int* col = ei + E;
    const int K = (N + BIN_SIZE - 1) >> BIN_SHIFT;  // 977 for N=500K

    float* ws   = (float*)d_ws;
    float* dinv = ws;                        // N floats
    float* acc1 = ws + (size_t)N;            // 8N floats
    half8* g0   = (half8*)(ws + (size_t)9  * N);  // 4N floats worth (f16x8 per node)
    half2v* g1  = (half2v*)(ws + (size_t)13 * N); // N floats worth (f16x2 per node)
    int*   meta = (int*)(ws + (size_t)14 * N);
    int* ghist   = meta;                     // K ints
    int* binBase = meta + MAXK;              // K+1 ints
    int* cursor  = meta + 2 * MAXK + 8;      // K ints
    unsigned* packed = (unsigned*)(meta + 4 * MAXK);  // E uints

    float* out = (float*)d_out;

    const int gN = (N + TPB - 1) / TPB;
    const int chunk = (E + NBLK_EDGE - 1) / NBLK_EDGE;

    k_zero_int   <<<1, MAXK, 0, stream>>>(ghist, K);
    k_hist       <<<NBLK_EDGE, TPB, 0, stream>>>(col, E, chunk, K, ghist);
    k_scan       <<<1, MAXK, 0, stream>>>(ghist, K, binBase, cursor);
    k_reorder    <<<NBLK_EDGE, TPB, 0, stream>>>(row, col, E, chunk, K, cursor, packed);
    k_binsort    <<<K, 512, 0, stream>>>(packed, binBase);
    k_deg_node1  <<<K, TPB, 0, stream>>>(packed, binBase, x, W1, dinv, g0, N);
    k_scatter1   <<<K, 512, 0, stream>>>(packed, binBase, g0, acc1, N);
    k_node2      <<<gN, TPB, 0, stream>>>(dinv, acc1, b1, W2, g1, N);
    k_scatter2_final<<<K, 512, 0, stream>>>(packed, binBase, g1, dinv, b2, out, N);
}

// Round 6
// 692.608 us; speedup vs baseline: 1.2496x; 1.2496x over previous
//
#include <hip/hip_runtime.h>

#define TPB 256
#define NBLK_EDGE 256          // blocks for hist/reorder; chunking must match between them
#define BIN_SHIFT 9
#define BIN_SIZE 512           // nodes per bin (= binsort block size)
#define MAXK 1024              // max bins (N=500K -> K=977)
#define ROW_BITS 19            // N=500,000 < 2^19
#define ROW_MASK ((1u << ROW_BITS) - 1)
#define CAP 16384              // binsort LDS staging capacity (64KB); mean bin = 8189 edges (+90 sigma)
#define SCRATCH_CAP (1 << 21)  // fallback scratch (g0 region) capacity in u32

typedef _Float16 half8  __attribute__((ext_vector_type(8)));
typedef _Float16 half2v __attribute__((ext_vector_type(2)));

__global__ void k_zero_int(int* __restrict__ p, int n) {
    int i = blockIdx.x * blockDim.x + threadIdx.x;
    if (i < n) p[i] = 0;
}

// Per-block LDS histogram of col>>BIN_SHIFT, merged with K atomics per block.
__global__ void k_hist(const int* __restrict__ col, int E, int chunk, int K,
                       int* __restrict__ ghist) {
    __shared__ int lh[MAXK];
    for (int k = threadIdx.x; k < K; k += blockDim.x) lh[k] = 0;
    __syncthreads();
    int s = blockIdx.x * chunk, e_ = min(s + chunk, E);
    for (int e = s + threadIdx.x; e < e_; e += blockDim.x)
        atomicAdd(&lh[col[e] >> BIN_SHIFT], 1);
    __syncthreads();
    for (int k = threadIdx.x; k < K; k += blockDim.x)
        if (lh[k]) atomicAdd(&ghist[k], lh[k]);
}

// Parallel exclusive scan over K<=MAXK bins (single block of MAXK threads).
__global__ void k_scan(const int* __restrict__ ghist, int K,
                       int* __restrict__ binBase, int* __restrict__ cursor) {
    __shared__ int tmp[MAXK];
    int tid = threadIdx.x;
    int val = (tid < K) ? ghist[tid] : 0;
    tmp[tid] = val;
    __syncthreads();
    for (int off = 1; off < MAXK; off <<= 1) {
        int v = (tid >= off) ? tmp[tid - off] : 0;
        __syncthreads();
        tmp[tid] += v;
        __syncthreads();
    }
    int incl = tmp[tid];
    int excl = incl - val;
    if (tid < K) { binBase[tid] = excl; cursor[tid] = excl; }
    if (tid == K - 1) binBase[K] = incl;  // == E
}

// Counting-sort reorder: per-block LDS hist -> block-level reservation in global
// cursor -> scatter packed edges (local_col<<19 | row) into bin-contiguous storage.
__global__ void k_reorder(const int* __restrict__ row, const int* __restrict__ col,
                          int E, int chunk, int K,
                          int* __restrict__ cursor, unsigned* __restrict__ packed) {
    __shared__ int lh[MAXK];
    for (int k = threadIdx.x; k < K; k += blockDim.x) lh[k] = 0;
    __syncthreads();
    int s = blockIdx.x * chunk, e_ = min(s + chunk, E);
    for (int e = s + threadIdx.x; e < e_; e += blockDim.x)
        atomicAdd(&lh[col[e] >> BIN_SHIFT], 1);
    __syncthreads();
    for (int k = threadIdx.x; k < K; k += blockDim.x) {
        int c = lh[k];
        lh[k] = c ? atomicAdd(&cursor[k], c) : 0;  // lh becomes running write cursor
    }
    __syncthreads();
    for (int e = s + threadIdx.x; e < e_; e += blockDim.x) {
        int c = col[e];
        int b = c >> BIN_SHIFT;
        unsigned lc = (unsigned)(c & (BIN_SIZE - 1));
        int pos = atomicAdd(&lh[b], 1);            // LDS atomic, returns slot
        packed[pos] = (lc << ROW_BITS) | (unsigned)row[e];
    }
}

// Full counting sort by destination node within each bin -> CSR. cnt[] is the
// per-node degree for free: writes dinv = rsqrt(deg+1) and nodeptr (global edge
// base per node). In-place via LDS staging; oversized bins (>CAP) stage through
// global scratch (ticketed) so correctness never depends on CAP.
__global__ void __launch_bounds__(512) k_binsort_deg(
        unsigned* __restrict__ packed, const int* __restrict__ binBase,
        unsigned* __restrict__ scratch, int* __restrict__ scratchCur,
        float* __restrict__ dinv, int* __restrict__ nodeptr, int N, int E, int K) {
    __shared__ unsigned buf[CAP];      // 64 KB
    __shared__ int cnt[BIN_SIZE], cur[BIN_SIZE];
    __shared__ int sbShared;
    int tid = threadIdx.x;
    int bin = blockIdx.x;
    int s = binBase[bin], t = binBase[bin + 1];
    int len = t - s;
    bool fast = (len <= CAP);
    for (int i = tid; i < BIN_SIZE; i += blockDim.x) cnt[i] = 0;
    if (!fast && tid == 0) sbShared = atomicAdd(scratchCur, len);
    __syncthreads();
    unsigned* stage = fast ? buf : (scratch + sbShared);
    // stage + degree count (1 LDS atomic per edge)
    for (int i = tid; i < len; i += blockDim.x) {
        unsigned v = packed[s + i];
        stage[i] = v;
        atomicAdd(&cnt[v >> ROW_BITS], 1);
    }
    __syncthreads();
    // exclusive scan of cnt (blockDim == BIN_SIZE)
    int val = cnt[tid];
    cur[tid] = val;
    __syncthreads();
    for (int off = 1; off < BIN_SIZE; off <<= 1) {
        int v = (tid >= off) ? cur[tid - off] : 0;
        __syncthreads();
        cur[tid] += v;
        __syncthreads();
    }
    int excl = cur[tid] - val;
    int base = bin << BIN_SHIFT;
    if (base + tid < N) {
        nodeptr[base + tid] = s + excl;
        dinv[base + tid] = rsqrtf((float)(val + 1));  // +1 self-loop
    }
    if (bin == K - 1 && tid == 0) nodeptr[N] = E;
    __syncthreads();
    cur[tid] = excl;  // becomes running placement cursor
    __syncthreads();
    for (int i = tid; i < len; i += blockDim.x) {
        unsigned v = stage[i];
        int slot = atomicAdd(&cur[v >> ROW_BITS], 1);
        packed[s + slot] = v;
    }
}

// g0 = f16(dinv * (x @ W1)) — pure per-node, no edge work.
__global__ void k_node1(const float* __restrict__ x, const float* __restrict__ W1,
                        const float* __restrict__ dinv_arr, half8* __restrict__ g0, int N) {
    int i = blockIdx.x * blockDim.x + threadIdx.x;
    if (i >= N) return;
    float di = dinv_arr[i];
    const float4* xv = (const float4*)(x + (size_t)i * 16);
    float4 a0 = xv[0], a1 = xv[1], a2 = xv[2], a3 = xv[3];
    float xl[16] = {a0.x, a0.y, a0.z, a0.w, a1.x, a1.y, a1.z, a1.w,
                    a2.x, a2.y, a2.z, a2.w, a3.x, a3.y, a3.z, a3.w};
    float h[8];
#pragma unroll
    for (int j = 0; j < 8; ++j) h[j] = 0.0f;
#pragma unroll
    for (int k = 0; k < 16; ++k) {
        float xk = xl[k];
#pragma unroll
        for (int j = 0; j < 8; ++j) h[j] += xk * W1[k * 8 + j];
    }
    half8 g;
#pragma unroll
    for (int j = 0; j < 8; ++j) g[j] = (_Float16)(di * h[j]);
    g0[i] = g;
}

// CSR gather layer 1 fused with node2 MLP. Thread per node: register
// accumulation over the node's edge segment — ZERO atomics.
__global__ void k_gather1_node2(const unsigned* __restrict__ packed,
                                const int* __restrict__ nodeptr,
                                const half8* __restrict__ g0,
                                const float* __restrict__ dinv_arr,
                                const float* __restrict__ b1,
                                const float* __restrict__ W2,
                                half2v* __restrict__ g1, int N) {
    int i = blockIdx.x * blockDim.x + threadIdx.x;
    if (i >= N) return;
    int s = nodeptr[i], t = nodeptr[i + 1];
    half8 self = g0[i];
    float acc[8];
#pragma unroll
    for (int j = 0; j < 8; ++j) acc[j] = (float)self[j];  // self-loop
    for (int e = s; e < t; ++e) {
        half8 v = g0[packed[e] & ROW_MASK];
#pragma unroll
        for (int j = 0; j < 8; ++j) acc[j] += (float)v[j];
    }
    float di = dinv_arr[i];
    float o0 = 0.0f, o1 = 0.0f;
#pragma unroll
    for (int j = 0; j < 8; ++j) {
        float hj = fmaxf(di * acc[j] + b1[j], 0.0f);
        o0 += hj * W2[j * 2 + 0];
        o1 += hj * W2[j * 2 + 1];
    }
    half2v g;
    g.x = (_Float16)(di * o0);
    g.y = (_Float16)(di * o1);
    g1[i] = g;
}

// CSR gather layer 2 fused with log-softmax epilogue. Zero atomics.
__global__ void k_gather2_final(const unsigned* __restrict__ packed,
                                const int* __restrict__ nodeptr,
                                const half2v* __restrict__ g1,
                                const float* __restrict__ dinv_arr,
                                const float* __restrict__ b2,
                                float* __restrict__ out, int N) {
    int i = blockIdx.x * blockDim.x + threadIdx.x;
    if (i >= N) return;
    int s = nodeptr[i], t = nodeptr[i + 1];
    half2v sg = g1[i];
    float a0 = (float)sg.x, a1 = (float)sg.y;  // self-loop
    for (int e = s; e < t; ++e) {
        half2v v = g1[packed[e] & ROW_MASK];
        a0 += (float)v.x;
        a1 += (float)v.y;
    }
    float di = dinv_arr[i];
    float o0 = di * a0 + b2[0];
    float o1 = di * a1 + b2[1];
    float m = fmaxf(o0, o1);
    float lse = m + logf(expf(o0 - m) + expf(o1 - m));
    ((float2*)out)[i] = make_float2(o0 - lse, o1 - lse);
}

extern "C" void kernel_launch(void* const* d_in, const int* in_sizes, int n_in,
                              void* d_out, int out_size, void* d_ws, size_t ws_size,
                              hipStream_t stream) {
    const float* x  = (const float*)d_in[0];
    const float* W1 = (const float*)d_in[1];
    const float* b1 = (const float*)d_in[2];
    const float* W2 = (const float*)d_in[3];
    const float* b2 = (const float*)d_in[4];
    const int*   ei = (const int*)d_in[5];

    const int N = in_sizes[0] / 16;
    const int E = in_sizes[5] / 2;
    const int* row = ei;
    const int* col = ei + E;
    const int K = (N + BIN_SIZE - 1) >> BIN_SHIFT;  // 977 for N=500K

    float* ws   = (float*)d_ws;
    float* dinv = ws;                              // N floats
    half8* g0   = (half8*)(ws + (size_t)N);        // 4N floats worth (f16x8/node);
                                                   //   also binsort fallback scratch (runs before node1)
    half2v* g1  = (half2v*)(ws + (size_t)5 * N);   // N floats worth (f16x2/node)
    int* nodeptr = (int*)(ws + (size_t)6 * N);     // N+1 ints
    int*   meta = (int*)(ws + (size_t)7 * N + 8);
    int* ghist      = meta;                        // K ints
    int* binBase    = meta + MAXK;                 // K+1 ints
    int* cursor     = meta + 2 * MAXK + 8;         // K ints
    int* scratchCur = meta + 3 * MAXK;             // 1 int (ticket for oversized bins)
    unsigned* packed = (unsigned*)(meta + 4 * MAXK);  // E uints

    float* out = (float*)d_out;

    const int gN = (N + TPB - 1) / TPB;
    const int chunk = (E + NBLK_EDGE - 1) / NBLK_EDGE;

    k_zero_int   <<<(4 * MAXK + TPB - 1) / TPB, TPB, 0, stream>>>(meta, 4 * MAXK);
    k_hist       <<<NBLK_EDGE, TPB, 0, stream>>>(col, E, chunk, K, ghist);
    k_scan       <<<1, MAXK, 0, stream>>>(ghist, K, binBase, cursor);
    k_reorder    <<<NBLK_EDGE, TPB, 0, stream>>>(row, col, E, chunk, K, cursor, packed);
    k_binsort_deg<<<K, BIN_SIZE, 0, stream>>>(packed, binBase, (unsigned*)g0, scratchCur,
                                              dinv, nodeptr, N, E, K);
    k_node1      <<<gN, TPB, 0, stream>>>(x, W1, dinv, g0, N);
    k_gather1_node2<<<gN, TPB, 0, stream>>>(packed, nodeptr, g0, dinv, b1, W2, g1, N);
    k_gather2_final<<<gN, TPB, 0, stream>>>(packed, nodeptr, g1, dinv, b2, out, N);
}

// Round 7
// 539.593 us; speedup vs baseline: 1.6039x; 1.2836x over previous
//
#include <hip/hip_runtime.h>

#define TPB 256
#define NBLK_EDGE 1024         // blocks for hist/reorder; chunking must match between them
#define BIN_SHIFT 9
#define BIN_SIZE 512           // nodes per bin (= binsort block size)
#define MAXK 1024              // max bins (N=500K -> K=977)
#define ROW_BITS 19            // N=500,000 < 2^19
#define ROW_MASK ((1u << ROW_BITS) - 1)
#define CAP 12288              // binsort LDS staging (48KB); mean bin = 8189 edges (+45 sigma)

typedef _Float16 half8  __attribute__((ext_vector_type(8)));
typedef _Float16 half2v __attribute__((ext_vector_type(2)));

__global__ void k_zero_int(int* __restrict__ p, int n) {
    int i = blockIdx.x * blockDim.x + threadIdx.x;
    if (i < n) p[i] = 0;
}

// Per-block LDS histogram of col>>BIN_SHIFT, merged with K atomics per block.
__global__ void k_hist(const int* __restrict__ col, int E, int chunk, int K,
                       int* __restrict__ ghist) {
    __shared__ int lh[MAXK];
    for (int k = threadIdx.x; k < K; k += blockDim.x) lh[k] = 0;
    __syncthreads();
    int s = blockIdx.x * chunk, e_ = min(s + chunk, E);
    for (int e = s + threadIdx.x; e < e_; e += blockDim.x)
        atomicAdd(&lh[col[e] >> BIN_SHIFT], 1);
    __syncthreads();
    for (int k = threadIdx.x; k < K; k += blockDim.x)
        if (lh[k]) atomicAdd(&ghist[k], lh[k]);
}

// Parallel exclusive scan over K<=MAXK bins (single block of MAXK threads).
__global__ void k_scan(const int* __restrict__ ghist, int K,
                       int* __restrict__ binBase, int* __restrict__ cursor) {
    __shared__ int tmp[MAXK];
    int tid = threadIdx.x;
    int val = (tid < K) ? ghist[tid] : 0;
    tmp[tid] = val;
    __syncthreads();
    for (int off = 1; off < MAXK; off <<= 1) {
        int v = (tid >= off) ? tmp[tid - off] : 0;
        __syncthreads();
        tmp[tid] += v;
        __syncthreads();
    }
    int incl = tmp[tid];
    int excl = incl - val;
    if (tid < K) { binBase[tid] = excl; cursor[tid] = excl; }
    if (tid == K - 1) binBase[K] = incl;  // == E
}

// Counting-sort reorder: per-block LDS hist -> block-level reservation in global
// cursor -> scatter packed edges (local_col<<19 | row) into bin-contiguous storage.
__global__ void k_reorder(const int* __restrict__ row, const int* __restrict__ col,
                          int E, int chunk, int K,
                          int* __restrict__ cursor, unsigned* __restrict__ packed) {
    __shared__ int lh[MAXK];
    for (int k = threadIdx.x; k < K; k += blockDim.x) lh[k] = 0;
    __syncthreads();
    int s = blockIdx.x * chunk, e_ = min(s + chunk, E);
    for (int e = s + threadIdx.x; e < e_; e += blockDim.x)
        atomicAdd(&lh[col[e] >> BIN_SHIFT], 1);
    __syncthreads();
    for (int k = threadIdx.x; k < K; k += blockDim.x) {
        int c = lh[k];
        lh[k] = c ? atomicAdd(&cursor[k], c) : 0;  // lh becomes running write cursor
    }
    __syncthreads();
    for (int e = s + threadIdx.x; e < e_; e += blockDim.x) {
        int c = col[e];
        int b = c >> BIN_SHIFT;
        unsigned lc = (unsigned)(c & (BIN_SIZE - 1));
        int pos = atomicAdd(&lh[b], 1);            // LDS atomic, returns slot
        packed[pos] = (lc << ROW_BITS) | (unsigned)row[e];
    }
}

// Full counting sort by destination node within each bin -> CSR. cnt[] is the
// per-node degree for free: writes dinv = rsqrt(deg+1) and nodeptr (global edge
// base per node). In-place via LDS staging; oversized bins (>CAP) stage through
// global scratch (ticketed) so correctness never depends on CAP.
__global__ void __launch_bounds__(512) k_binsort_deg(
        unsigned* __restrict__ packed, const int* __restrict__ binBase,
        unsigned* __restrict__ scratch, int* __restrict__ scratchCur,
        float* __restrict__ dinv, int* __restrict__ nodeptr, int N, int E, int K) {
    __shared__ unsigned buf[CAP];      // 48 KB
    __shared__ int cnt[BIN_SIZE], cur[BIN_SIZE];
    __shared__ int sbShared;
    int tid = threadIdx.x;
    int bin = blockIdx.x;
    int s = binBase[bin], t = binBase[bin + 1];
    int len = t - s;
    bool fast = (len <= CAP);
    for (int i = tid; i < BIN_SIZE; i += blockDim.x) cnt[i] = 0;
    if (!fast && tid == 0) sbShared = atomicAdd(scratchCur, len);
    __syncthreads();
    unsigned* stage = fast ? buf : (scratch + sbShared);
    // stage + degree count (1 LDS atomic per edge)
    for (int i = tid; i < len; i += blockDim.x) {
        unsigned v = packed[s + i];
        stage[i] = v;
        atomicAdd(&cnt[v >> ROW_BITS], 1);
    }
    __syncthreads();
    // exclusive scan of cnt (blockDim == BIN_SIZE)
    int val = cnt[tid];
    cur[tid] = val;
    __syncthreads();
    for (int off = 1; off < BIN_SIZE; off <<= 1) {
        int v = (tid >= off) ? cur[tid - off] : 0;
        __syncthreads();
        cur[tid] += v;
        __syncthreads();
    }
    int excl = cur[tid] - val;
    int base = bin << BIN_SHIFT;
    if (base + tid < N) {
        nodeptr[base + tid] = s + excl;
        dinv[base + tid] = rsqrtf((float)(val + 1));  // +1 self-loop
    }
    if (bin == K - 1 && tid == 0) nodeptr[N] = E;
    __syncthreads();
    cur[tid] = excl;  // becomes running placement cursor
    __syncthreads();
    for (int i = tid; i < len; i += blockDim.x) {
        unsigned v = stage[i];
        int slot = atomicAdd(&cur[v >> ROW_BITS], 1);
        packed[s + slot] = v;
    }
}

// g0 = f16(dinv * (x @ W1)) — pure per-node, no edge work.
__global__ void k_node1(const float* __restrict__ x, const float* __restrict__ W1,
                        const float* __restrict__ dinv_arr, half8* __restrict__ g0, int N) {
    int i = blockIdx.x * blockDim.x + threadIdx.x;
    if (i >= N) return;
    float di = dinv_arr[i];
    const float4* xv = (const float4*)(x + (size_t)i * 16);
    float4 a0 = xv[0], a1 = xv[1], a2 = xv[2], a3 = xv[3];
    float xl[16] = {a0.x, a0.y, a0.z, a0.w, a1.x, a1.y, a1.z, a1.w,
                    a2.x, a2.y, a2.z, a2.w, a3.x, a3.y, a3.z, a3.w};
    float h[8];
#pragma unroll
    for (int j = 0; j < 8; ++j) h[j] = 0.0f;
#pragma unroll
    for (int k = 0; k < 16; ++k) {
        float xk = xl[k];
#pragma unroll
        for (int j = 0; j < 8; ++j) h[j] += xk * W1[k * 8 + j];
    }
    half8 g;
#pragma unroll
    for (int j = 0; j < 8; ++j) g[j] = (_Float16)(di * h[j]);
    g0[i] = g;
}

// CSR gather layer 1 fused with node2 MLP. Thread per node, register
// accumulation, zero atomics. 4x unrolled: 4 independent gathers in flight.
__global__ void k_gather1_node2(const unsigned* __restrict__ packed,
                                const int* __restrict__ nodeptr,
                                const half8* __restrict__ g0,
                                const float* __restrict__ dinv_arr,
                                const float* __restrict__ b1,
                                const float* __restrict__ W2,
                                half2v* __restrict__ g1, int N) {
    int i = blockIdx.x * blockDim.x + threadIdx.x;
    if (i >= N) return;
    int s = nodeptr[i], t = nodeptr[i + 1];
    half8 self = g0[i];
    float acc[8];
#pragma unroll
    for (int j = 0; j < 8; ++j) acc[j] = (float)self[j];  // self-loop
    int e = s;
    for (; e + 4 <= t; e += 4) {
        unsigned p0 = packed[e], p1 = packed[e + 1], p2 = packed[e + 2], p3 = packed[e + 3];
        half8 v0 = g0[p0 & ROW_MASK];
        half8 v1 = g0[p1 & ROW_MASK];
        half8 v2 = g0[p2 & ROW_MASK];
        half8 v3 = g0[p3 & ROW_MASK];
#pragma unroll
        for (int j = 0; j < 8; ++j)
            acc[j] += (float)v0[j] + (float)v1[j] + (float)v2[j] + (float)v3[j];
    }
    for (; e < t; ++e) {
        half8 v = g0[packed[e] & ROW_MASK];
#pragma unroll
        for (int j = 0; j < 8; ++j) acc[j] += (float)v[j];
    }
    float di = dinv_arr[i];
    float o0 = 0.0f, o1 = 0.0f;
#pragma unroll
    for (int j = 0; j < 8; ++j) {
        float hj = fmaxf(di * acc[j] + b1[j], 0.0f);
        o0 += hj * W2[j * 2 + 0];
        o1 += hj * W2[j * 2 + 1];
    }
    half2v g;
    g.x = (_Float16)(di * o0);
    g.y = (_Float16)(di * o1);
    g1[i] = g;
}

// CSR gather layer 2 fused with log-softmax epilogue. Zero atomics, 4x unrolled.
__global__ void k_gather2_final(const unsigned* __restrict__ packed,
                                const int* __restrict__ nodeptr,
                                const half2v* __restrict__ g1,
                                const float* __restrict__ dinv_arr,
                                const float* __restrict__ b2,
                                float* __restrict__ out, int N) {
    int i = blockIdx.x * blockDim.x + threadIdx.x;
    if (i >= N) return;
    int s = nodeptr[i], t = nodeptr[i + 1];
    half2v sg = g1[i];
    float a0 = (float)sg.x, a1 = (float)sg.y;  // self-loop
    int e = s;
    for (; e + 4 <= t; e += 4) {
        unsigned p0 = packed[e], p1 = packed[e + 1], p2 = packed[e + 2], p3 = packed[e + 3];
        half2v v0 = g1[p0 & ROW_MASK];
        half2v v1 = g1[p1 & ROW_MASK];
        half2v v2 = g1[p2 & ROW_MASK];
        half2v v3 = g1[p3 & ROW_MASK];
        a0 += (float)v0.x + (float)v1.x + (float)v2.x + (float)v3.x;
        a1 += (float)v0.y + (float)v1.y + (float)v2.y + (float)v3.y;
    }
    for (; e < t; ++e) {
        half2v v = g1[packed[e] & ROW_MASK];
        a0 += (float)v.x;
        a1 += (float)v.y;
    }
    float di = dinv_arr[i];
    float o0 = di * a0 + b2[0];
    float o1 = di * a1 + b2[1];
    float m = fmaxf(o0, o1);
    float lse = m + logf(expf(o0 - m) + expf(o1 - m));
    ((float2*)out)[i] = make_float2(o0 - lse, o1 - lse);
}

extern "C" void kernel_launch(void* const* d_in, const int* in_sizes, int n_in,
                              void* d_out, int out_size, void* d_ws, size_t ws_size,
                              hipStream_t stream) {
    const float* x  = (const float*)d_in[0];
    const float* W1 = (const float*)d_in[1];
    const float* b1 = (const float*)d_in[2];
    const float* W2 = (const float*)d_in[3];
    const float* b2 = (const float*)d_in[4];
    const int*   ei = (const int*)d_in[5];

    const int N = in_sizes[0] / 16;
    const int E = in_sizes[5] / 2;
    const int* row = ei;
    const int* col = ei + E;
    const int K = (N + BIN_SIZE - 1) >> BIN_SHIFT;  // 977 for N=500K

    float* ws   = (float*)d_ws;
    float* dinv = ws;                              // N floats
    half8* g0   = (half8*)(ws + (size_t)N);        // 4N floats worth (f16x8/node);
                                                   //   also binsort fallback scratch (runs before node1)
    half2v* g1  = (half2v*)(ws + (size_t)5 * N);   // N floats worth (f16x2/node)
    int* nodeptr = (int*)(ws + (size_t)6 * N);     // N+1 ints
    int*   meta = (int*)(ws + (size_t)7 * N + 8);
    int* ghist      = meta;                        // K ints
    int* binBase    = meta + MAXK;                 // K+1 ints
    int* cursor     = meta + 2 * MAXK + 8;         // K ints
    int* scratchCur = meta + 3 * MAXK;             // 1 int (ticket for oversized bins)
    unsigned* packed = (unsigned*)(meta + 4 * MAXK);  // E uints

    float* out = (float*)d_out;

    const int gN = (N + TPB - 1) / TPB;
    const int chunk = (E + NBLK_EDGE - 1) / NBLK_EDGE;

    k_zero_int   <<<(4 * MAXK + TPB - 1) / TPB, TPB, 0, stream>>>(meta, 4 * MAXK);
    k_hist       <<<NBLK_EDGE, TPB, 0, stream>>>(col, E, chunk, K, ghist);
    k_scan       <<<1, MAXK, 0, stream>>>(ghist, K, binBase, cursor);
    k_reorder    <<<NBLK_EDGE, TPB, 0, stream>>>(row, col, E, chunk, K, cursor, packed);
    k_binsort_deg<<<K, BIN_SIZE, 0, stream>>>(packed, binBase, (unsigned*)g0, scratchCur,
                                              dinv, nodeptr, N, E, K);
    k_node1      <<<gN, TPB, 0, stream>>>(x, W1, dinv, g0, N);
    k_gather1_node2<<<gN, TPB, 0, stream>>>(packed, nodeptr, g0, dinv, b1, W2, g1, N);
    k_gather2_final<<<gN, TPB, 0, stream>>>(packed, nodeptr, g1, dinv, b2, out, N);
}

// Round 8
// 439.064 us; speedup vs baseline: 1.9711x; 1.2290x over previous
//
#include <hip/hip_runtime.h>

#define TPB 256
#define NBLK_EDGE 1024         // blocks for hist/reorder; chunking must match between them
#define CHUNKE 8192            // max edges per reorder block (E/NBLK rounded up fits)
#define BIN_SHIFT 9
#define BIN_SIZE 512           // nodes per bin (= binsort block size)
#define MAXK 1024              // max bins (N=500K -> K=977)
#define ROW_BITS 19            // N=500,000 < 2^19
#define ROW_MASK ((1u << ROW_BITS) - 1)
#define CAP 12288              // binsort LDS staging (48KB); mean bin = 8189 edges (+45 sigma)

typedef _Float16 half8  __attribute__((ext_vector_type(8)));
typedef _Float16 half2v __attribute__((ext_vector_type(2)));

__global__ void k_zero_int(int* __restrict__ p, int n) {
    int i = blockIdx.x * blockDim.x + threadIdx.x;
    if (i < n) p[i] = 0;
}

// Per-block LDS histogram of col>>BIN_SHIFT; persists per-block rows in BOTH
// layouts: cntB (block-major, coalesced reload in k_reorder) and cntT
// (bin-major, coalesced scan in k_colscan). No global atomics.
__global__ void k_hist(const int* __restrict__ col, int E, int chunk, int K,
                       int* __restrict__ cntB, int* __restrict__ cntT) {
    __shared__ int lh[MAXK];
    int blk = blockIdx.x;
    for (int k = threadIdx.x; k < MAXK; k += blockDim.x) lh[k] = 0;
    __syncthreads();
    int s = blk * chunk, e_ = min(s + chunk, E);
    for (int e = s + threadIdx.x; e < e_; e += blockDim.x)
        atomicAdd(&lh[col[e] >> BIN_SHIFT], 1);
    __syncthreads();
    for (int k = threadIdx.x; k < MAXK; k += blockDim.x) {
        int v = lh[k];
        cntB[(size_t)blk * MAXK + k] = v;               // coalesced
        cntT[(size_t)k * NBLK_EDGE + blk] = v;          // scattered (1024/block)
    }
}

// Per-bin exclusive scan over the NBLK_EDGE per-block counts (in-place) and
// per-bin total -> ghist. One block per bin, coalesced row access.
__global__ void k_colscan(int* __restrict__ cntT, int* __restrict__ ghist) {
    __shared__ int part[256];
    int b = blockIdx.x, tid = threadIdx.x;
    size_t base = (size_t)b * NBLK_EDGE;
    int t4 = tid * 4;
    int c0 = cntT[base + t4], c1 = cntT[base + t4 + 1],
        c2 = cntT[base + t4 + 2], c3 = cntT[base + t4 + 3];
    int sum = c0 + c1 + c2 + c3;
    part[tid] = sum;
    __syncthreads();
    for (int off = 1; off < 256; off <<= 1) {
        int v = (tid >= off) ? part[tid - off] : 0;
        __syncthreads();
        part[tid] += v;
        __syncthreads();
    }
    int excl = part[tid] - sum;
    cntT[base + t4]     = excl;
    cntT[base + t4 + 1] = excl + c0;
    cntT[base + t4 + 2] = excl + c0 + c1;
    cntT[base + t4 + 3] = excl + c0 + c1 + c2;
    if (tid == 255) ghist[b] = part[255];  // bin total
}

// Parallel exclusive scan over K<=MAXK bins (single block of MAXK threads).
__global__ void k_scan(const int* __restrict__ ghist, int K, int* __restrict__ binBase) {
    __shared__ int tmp[MAXK];
    int tid = threadIdx.x;
    int val = (tid < K) ? ghist[tid] : 0;
    tmp[tid] = val;
    __syncthreads();
    for (int off = 1; off < MAXK; off <<= 1) {
        int v = (tid >= off) ? tmp[tid - off] : 0;
        __syncthreads();
        tmp[tid] += v;
        __syncthreads();
    }
    int incl = tmp[tid];
    if (tid < K) binBase[tid] = incl - val;
    if (tid == K - 1) binBase[K] = incl;  // == E
}

// Reorder with LOCAL SORT: place the block's chunk bin-sorted in LDS, then
// write out in contiguous per-bin runs (~8 edges = 32B per run) so each wave
// store is ~8 transactions instead of 64 scattered 4B lanes. Placement bases
// are precomputed (binBase + scanned cntT), so no global atomics at all.
__global__ void __launch_bounds__(256) k_reorder(
        const int* __restrict__ row, const int* __restrict__ col,
        int E, int chunk, int K,
        const int* __restrict__ binBase, const int* __restrict__ cntB,
        const int* __restrict__ cntT, unsigned* __restrict__ packed) {
    __shared__ unsigned sorted[CHUNKE];       // 32 KB
    __shared__ unsigned short sbin[CHUNKE];   // 16 KB
    __shared__ int lcur[MAXK], lbase[MAXK], gbase[MAXK];  // 12 KB
    __shared__ int part[256];
    int blk = blockIdx.x, tid = threadIdx.x;
    int s = blk * chunk, e_ = min(s + chunk, E), len = e_ - s;
    // local exclusive scan of this block's per-bin counts
    int t4 = tid * 4;
    size_t bb = (size_t)blk * MAXK;
    int c0 = cntB[bb + t4], c1 = cntB[bb + t4 + 1],
        c2 = cntB[bb + t4 + 2], c3 = cntB[bb + t4 + 3];
    int sum = c0 + c1 + c2 + c3;
    part[tid] = sum;
    __syncthreads();
    for (int off = 1; off < 256; off <<= 1) {
        int v = (tid >= off) ? part[tid - off] : 0;
        __syncthreads();
        part[tid] += v;
        __syncthreads();
    }
    int excl = part[tid] - sum;
    lbase[t4] = excl;           lcur[t4] = excl;
    lbase[t4 + 1] = excl + c0;  lcur[t4 + 1] = excl + c0;
    lbase[t4 + 2] = excl + c0 + c1;       lcur[t4 + 2] = excl + c0 + c1;
    lbase[t4 + 3] = excl + c0 + c1 + c2;  lcur[t4 + 3] = excl + c0 + c1 + c2;
    for (int k = tid; k < K; k += blockDim.x)
        gbase[k] = binBase[k] + cntT[(size_t)k * NBLK_EDGE + blk];
    __syncthreads();
    // placement: bin-sorted staging in LDS (1 LDS atomic per edge)
    for (int i = tid; i < len; i += blockDim.x) {
        int c = col[s + i];
        int b = c >> BIN_SHIFT;
        int slot = atomicAdd(&lcur[b], 1);
        sorted[slot] = ((unsigned)(c & (BIN_SIZE - 1)) << ROW_BITS) | (unsigned)row[s + i];
        sbin[slot] = (unsigned short)b;
    }
    __syncthreads();
    // coalesced run write-out
    for (int i = tid; i < len; i += blockDim.x) {
        int b = sbin[i];
        packed[gbase[b] + (i - lbase[b])] = sorted[i];
    }
}

// Full counting sort by destination node within each bin -> CSR. cnt[] is the
// per-node degree for free: writes dinv = rsqrt(deg+1) and nodeptr (global edge
// base per node). In-place via LDS staging; oversized bins (>CAP) stage through
// global scratch (ticketed) so correctness never depends on CAP.
__global__ void __launch_bounds__(512) k_binsort_deg(
        unsigned* __restrict__ packed, const int* __restrict__ binBase,
        unsigned* __restrict__ scratch, int* __restrict__ scratchCur,
        float* __restrict__ dinv, int* __restrict__ nodeptr, int N, int E, int K) {
    __shared__ unsigned buf[CAP];      // 48 KB
    __shared__ int cnt[BIN_SIZE], cur[BIN_SIZE];
    __shared__ int sbShared;
    int tid = threadIdx.x;
    int bin = blockIdx.x;
    int s = binBase[bin], t = binBase[bin + 1];
    int len = t - s;
    bool fast = (len <= CAP);
    for (int i = tid; i < BIN_SIZE; i += blockDim.x) cnt[i] = 0;
    if (!fast && tid == 0) sbShared = atomicAdd(scratchCur, len);
    __syncthreads();
    unsigned* stage = fast ? buf : (scratch + sbShared);
    for (int i = tid; i < len; i += blockDim.x) {
        unsigned v = packed[s + i];
        stage[i] = v;
        atomicAdd(&cnt[v >> ROW_BITS], 1);
    }
    __syncthreads();
    int val = cnt[tid];
    cur[tid] = val;
    __syncthreads();
    for (int off = 1; off < BIN_SIZE; off <<= 1) {
        int v = (tid >= off) ? cur[tid - off] : 0;
        __syncthreads();
        cur[tid] += v;
        __syncthreads();
    }
    int excl = cur[tid] - val;
    int base = bin << BIN_SHIFT;
    if (base + tid < N) {
        nodeptr[base + tid] = s + excl;
        dinv[base + tid] = rsqrtf((float)(val + 1));  // +1 self-loop
    }
    if (bin == K - 1 && tid == 0) nodeptr[N] = E;
    __syncthreads();
    cur[tid] = excl;  // becomes running placement cursor
    __syncthreads();
    for (int i = tid; i < len; i += blockDim.x) {
        unsigned v = stage[i];
        int slot = atomicAdd(&cur[v >> ROW_BITS], 1);
        packed[s + slot] = v;
    }
}

// g0 = f16(dinv * (x @ W1)) — pure per-node, no edge work.
__global__ void k_node1(const float* __restrict__ x, const float* __restrict__ W1,
                        const float* __restrict__ dinv_arr, half8* __restrict__ g0, int N) {
    int i = blockIdx.x * blockDim.x + threadIdx.x;
    if (i >= N) return;
    float di = dinv_arr[i];
    const float4* xv = (const float4*)(x + (size_t)i * 16);
    float4 a0 = xv[0], a1 = xv[1], a2 = xv[2], a3 = xv[3];
    float xl[16] = {a0.x, a0.y, a0.z, a0.w, a1.x, a1.y, a1.z, a1.w,
                    a2.x, a2.y, a2.z, a2.w, a3.x, a3.y, a3.z, a3.w};
    float h[8];
#pragma unroll
    for (int j = 0; j < 8; ++j) h[j] = 0.0f;
#pragma unroll
    for (int k = 0; k < 16; ++k) {
        float xk = xl[k];
#pragma unroll
        for (int j = 0; j < 8; ++j) h[j] += xk * W1[k * 8 + j];
    }
    half8 g;
#pragma unroll
    for (int j = 0; j < 8; ++j) g[j] = (_Float16)(di * h[j]);
    g0[i] = g;
}

// CSR gather layer 1 fused with node2 MLP. Thread per node, register
// accumulation, zero atomics. 4x unrolled: 4 independent gathers in flight.
__global__ void k_gather1_node2(const unsigned* __restrict__ packed,
                                const int* __restrict__ nodeptr,
                                const half8* __restrict__ g0,
                                const float* __restrict__ dinv_arr,
                                const float* __restrict__ b1,
                                const float* __restrict__ W2,
                                half2v* __restrict__ g1, int N) {
    int i = blockIdx.x * blockDim.x + threadIdx.x;
    if (i >= N) return;
    int s = nodeptr[i], t = nodeptr[i + 1];
    half8 self = g0[i];
    float acc[8];
#pragma unroll
    for (int j = 0; j < 8; ++j) acc[j] = (float)self[j];  // self-loop
    int e = s;
    for (; e + 4 <= t; e += 4) {
        unsigned p0 = packed[e], p1 = packed[e + 1], p2 = packed[e + 2], p3 = packed[e + 3];
        half8 v0 = g0[p0 & ROW_MASK];
        half8 v1 = g0[p1 & ROW_MASK];
        half8 v2 = g0[p2 & ROW_MASK];
        half8 v3 = g0[p3 & ROW_MASK];
#pragma unroll
        for (int j = 0; j < 8; ++j)
            acc[j] += (float)v0[j] + (float)v1[j] + (float)v2[j] + (float)v3[j];
    }
    for (; e < t; ++e) {
        half8 v = g0[packed[e] & ROW_MASK];
#pragma unroll
        for (int j = 0; j < 8; ++j) acc[j] += (float)v[j];
    }
    float di = dinv_arr[i];
    float o0 = 0.0f, o1 = 0.0f;
#pragma unroll
    for (int j = 0; j < 8; ++j) {
        float hj = fmaxf(di * acc[j] + b1[j], 0.0f);
        o0 += hj * W2[j * 2 + 0];
        o1 += hj * W2[j * 2 + 1];
    }
    half2v g;
    g.x = (_Float16)(di * o0);
    g.y = (_Float16)(di * o1);
    g1[i] = g;
}

// CSR gather layer 2 fused with log-softmax epilogue. Zero atomics, 4x unrolled.
__global__ void k_gather2_final(const unsigned* __restrict__ packed,
                                const int* __restrict__ nodeptr,
                                const half2v* __restrict__ g1,
                                const float* __restrict__ dinv_arr,
                                const float* __restrict__ b2,
                                float* __restrict__ out, int N) {
    int i = blockIdx.x * blockDim.x + threadIdx.x;
    if (i >= N) return;
    int s = nodeptr[i], t = nodeptr[i + 1];
    half2v sg = g1[i];
    float a0 = (float)sg.x, a1 = (float)sg.y;  // self-loop
    int e = s;
    for (; e + 4 <= t; e += 4) {
        unsigned p0 = packed[e], p1 = packed[e + 1], p2 = packed[e + 2], p3 = packed[e + 3];
        half2v v0 = g1[p0 & ROW_MASK];
        half2v v1 = g1[p1 & ROW_MASK];
        half2v v2 = g1[p2 & ROW_MASK];
        half2v v3 = g1[p3 & ROW_MASK];
        a0 += (float)v0.x + (float)v1.x + (float)v2.x + (float)v3.x;
        a1 += (float)v0.y + (float)v1.y + (float)v2.y + (float)v3.y;
    }
    for (; e < t; ++e) {
        half2v v = g1[packed[e] & ROW_MASK];
        a0 += (float)v.x;
        a1 += (float)v.y;
    }
    float di = dinv_arr[i];
    float o0 = di * a0 + b2[0];
    float o1 = di * a1 + b2[1];
    float m = fmaxf(o0, o1);
    float lse = m + logf(expf(o0 - m) + expf(o1 - m));
    ((float2*)out)[i] = make_float2(o0 - lse, o1 - lse);
}

extern "C" void kernel_launch(void* const* d_in, const int* in_sizes, int n_in,
                              void* d_out, int out_size, void* d_ws, size_t ws_size,
                              hipStream_t stream) {
    const float* x  = (const float*)d_in[0];
    const float* W1 = (const float*)d_in[1];
    const float* b1 = (const float*)d_in[2];
    const float* W2 = (const float*)d_in[3];
    const float* b2 = (const float*)d_in[4];
    const int*   ei = (const int*)d_in[5];

    const int N = in_sizes[0] / 16;
    const int E = in_sizes[5] / 2;
    const int* row = ei;
    const int* col = ei + E;
    const int K = (N + BIN_SIZE - 1) >> BIN_SHIFT;  // 977 for N=500K

    float* ws   = (float*)d_ws;
    float* dinv = ws;                              // N floats
    half8* g0   = (half8*)(ws + (size_t)N);        // 4N floats worth (f16x8/node);
                                                   //   also binsort fallback scratch
    half2v* g1  = (half2v*)(ws + (size_t)5 * N);   // N floats worth (f16x2/node)
    int* nodeptr = (int*)(ws + (size_t)6 * N);     // N+1 ints
    int*   meta = (int*)(ws + (size_t)7 * N + 8);
    int* ghist      = meta;                        // MAXK ints
    int* binBase    = meta + MAXK;                 // MAXK+1 ints (padded)
    int* scratchCur = meta + 2 * MAXK + 16;        // 1 int
    unsigned* packed = (unsigned*)(meta + 3 * MAXK);          // E uints
    int* cntB = (int*)(packed + E);                // MAXK*NBLK_EDGE ints (block-major)
    int* cntT = cntB + (size_t)MAXK * NBLK_EDGE;   // MAXK*NBLK_EDGE ints (bin-major)

    float* out = (float*)d_out;

    const int gN = (N + TPB - 1) / TPB;
    const int chunk = (E + NBLK_EDGE - 1) / NBLK_EDGE;  // <= CHUNKE

    k_zero_int   <<<1, 64, 0, stream>>>(scratchCur, 1);
    k_hist       <<<NBLK_EDGE, TPB, 0, stream>>>(col, E, chunk, K, cntB, cntT);
    k_colscan    <<<K, 256, 0, stream>>>(cntT, ghist);
    k_scan       <<<1, MAXK, 0, stream>>>(ghist, K, binBase);
    k_reorder    <<<NBLK_EDGE, TPB, 0, stream>>>(row, col, E, chunk, K,
                                                 binBase, cntB, cntT, packed);
    k_binsort_deg<<<K, BIN_SIZE, 0, stream>>>(packed, binBase, (unsigned*)g0, scratchCur,
                                              dinv, nodeptr, N, E, K);
    k_node1      <<<gN, TPB, 0, stream>>>(x, W1, dinv, g0, N);
    k_gather1_node2<<<gN, TPB, 0, stream>>>(packed, nodeptr, g0, dinv, b1, W2, g1, N);
    k_gather2_final<<<gN, TPB, 0, stream>>>(packed, nodeptr, g1, dinv, b2, out, N);
}